// Round 3
// baseline (219.263 us; speedup 1.0000x reference)
//
#include <hip/hip_runtime.h>
#include <hip/hip_bf16.h>
#include <math.h>

#define N_NODES 10000
#define N_EDGES 320000
#define CH 64
#define MIXW 192    // N_L * CH
#define EREC 12     // floats per edge record: sh[9] + snd + pad -> 48B rows

// weight-image layout (shorts), stride-72 rows (16B-aligned row starts)
#define W1_OFF 0        // [64][8]
#define W2_OFF 512      // [64][72]
#define W3_OFF 5120     // [64][72]
#define W4_OFF 9728     // [192][72]
#define W_TOT 23552     // shorts
#define ACT_STRIDE 72

#define EPB 256         // edges per k_mlp block (256 thr = 4 waves, 64 edges/wave)

// fused k_pre block ranges
#define PREP_BLKS 92            // 23552/256
#define H_BLKS 625              // 10000 nodes / (4 waves * 4 nodes-per-wave)
#define HIST_BLKS 1250          // 320000/256

typedef __attribute__((ext_vector_type(8))) short bf16x8;
typedef __attribute__((ext_vector_type(4))) float f32x4;
#define MFMA16(a, b, c) __builtin_amdgcn_mfma_f32_16x16x32_bf16(a, b, c, 0, 0, 0)

// ---------- small helpers ----------
__device__ __forceinline__ float bf2f(unsigned short u) {
    union { unsigned int i; float f; } v; v.i = ((unsigned int)u) << 16; return v.f;
}
__device__ __forceinline__ unsigned short f2bf(float f) {
    __hip_bfloat16 b = __float2bfloat16(f);
    return *reinterpret_cast<unsigned short*>(&b);
}
__device__ __forceinline__ float silu(float t) {
    return t * __builtin_amdgcn_rcpf(1.0f + __expf(-t));
}

// load a [64]->[64] layer's B-fragments (8 x b128 from L2-resident wimg)
__device__ __forceinline__ void load_bfrag(bf16x8 (&b)[4][2],
                                           const unsigned short* __restrict__ wbase,
                                           int lrow, int quad) {
#pragma unroll
    for (int nt = 0; nt < 4; ++nt)
#pragma unroll
        for (int kh = 0; kh < 2; ++kh)
            b[nt][kh] = *(const bf16x8*)(wbase + (nt * 16 + lrow) * 72 + kh * 32 + quad * 8);
}

// one in-place [64]->[64] MFMA layer with silu over FOUR 16-edge tiles.
// 8 independent MFMAs per nt -- 2x the ILP of the 2-tile version.
__device__ __forceinline__ void layer64_t4(unsigned short* act, const bf16x8 (&b)[4][2],
                                           const int (&em)[4], const int (&cr)[4],
                                           int lrow, int quad) {
    bf16x8 a[4][2];
#pragma unroll
    for (int t = 0; t < 4; ++t) {
        a[t][0] = *(const bf16x8*)(act + em[t] * ACT_STRIDE + quad * 8);
        a[t][1] = *(const bf16x8*)(act + em[t] * ACT_STRIDE + 32 + quad * 8);
    }
#pragma unroll
    for (int nt = 0; nt < 4; ++nt) {
        f32x4 c[4];
#pragma unroll
        for (int t = 0; t < 4; ++t) {
            c[t] = (f32x4){0.f, 0.f, 0.f, 0.f};
            c[t] = MFMA16(a[t][0], b[nt][0], c[t]);
            c[t] = MFMA16(a[t][1], b[nt][1], c[t]);
        }
#pragma unroll
        for (int t = 0; t < 4; ++t)
#pragma unroll
            for (int r = 0; r < 4; ++r)
                act[(cr[t] + r) * ACT_STRIDE + nt * 16 + lrow] = f2bf(silu(c[t][r]));
    }
}

// one third (64 cols) of layer 4 over 4 tiles: MFMA + stage + copyout to hw.
// No h-premultiply here anymore (applied in k_aggdown from f32 h).
__device__ __forceinline__ void l4_third_t4(unsigned short* act,
                                            const int* s_pos,
                                            unsigned short* __restrict__ hw,
                                            const bf16x8 (&b)[4][2],
                                            const bf16x8 (&a)[4][2],
                                            const int (&cr)[4],
                                            int T, int wr0, int lane, int lrow, int quad) {
#pragma unroll
    for (int nt = 0; nt < 4; ++nt) {
        f32x4 c[4];
#pragma unroll
        for (int t = 0; t < 4; ++t) {
            c[t] = (f32x4){0.f, 0.f, 0.f, 0.f};
            c[t] = MFMA16(a[t][0], b[nt][0], c[t]);
            c[t] = MFMA16(a[t][1], b[nt][1], c[t]);
        }
#pragma unroll
        for (int t = 0; t < 4; ++t)
#pragma unroll
            for (int r = 0; r < 4; ++r)
                act[(cr[t] + r) * ACT_STRIDE + nt * 16 + lrow] = f2bf(c[t][r]);
    }
    // copy wave's 64 rows x 64 cols -> hw[pos[row]][T*64 .. T*64+64)
#pragma unroll
    for (int j = 0; j < 8; ++j) {
        int idx = lane + 64 * j;          // 0..511
        int row = idx >> 3, c8 = idx & 7;
        int p = s_pos[wr0 + row];
        uint4 v = *(const uint4*)(act + (wr0 + row) * ACT_STRIDE + c8 * 8);
        *(uint4*)(hw + (size_t)p * MIXW + T * 64 + c8 * 8) = v;
    }
}

// ---------- K_pre: fused weight-prep + linear_up + receiver histogram ----------
// Scale folding: W1 *= 1/sqrt(8) (f32, then bf16); W2,W3 *= 1/8 (pow2, bit-exact);
// W4 *= 1/8 (pow2, bit-exact -- mlp4 scale now lives in the weight image);
// h = (nf@Wup)/8 in f32 (linear_up scale only; aggdown applies h per edge).
__global__ __launch_bounds__(256) void k_pre(const float* __restrict__ W1,
                                             const float* __restrict__ W2,
                                             const float* __restrict__ W3,
                                             const float* __restrict__ W4,
                                             unsigned short* __restrict__ wimg,
                                             const float* __restrict__ nf,
                                             const float* __restrict__ Wup,
                                             float* __restrict__ h,
                                             const int* __restrict__ recv,
                                             int* __restrict__ counts) {
    int bid = blockIdx.x;
    int t = threadIdx.x;
    if (bid < PREP_BLKS) {
        int i = bid * 256 + t;
        if (i >= W_TOT) return;
        float v;
        if (i < W2_OFF) {
            int n = i >> 3, k = i & 7;
            v = W1[k * 64 + n] * 0.35355339059327376f;
        } else if (i < W3_OFF) {
            int j = i - W2_OFF; int n = j / 72, k = j % 72;
            v = (k < 64) ? W2[k * 64 + n] * 0.125f : 0.f;
        } else if (i < W4_OFF) {
            int j = i - W3_OFF; int n = j / 72, k = j % 72;
            v = (k < 64) ? W3[k * 64 + n] * 0.125f : 0.f;
        } else {
            int j = i - W4_OFF; int n = j / 72, k = j % 72;
            v = (k < 64) ? W4[k * MIXW + n] * 0.125f : 0.f;
        }
        wimg[i] = f2bf(v);
    } else if (bid < PREP_BLKS + H_BLKS) {
        // linear_up: 4 nodes per wave -- Wup column loaded once, 4 indep chains
        int nb = __builtin_amdgcn_readfirstlane(
            (bid - PREP_BLKS) * 16 + (t >> 6) * 4);
        int lane = t & 63;
        const float* nrow = nf + (size_t)nb * CH;
        float a0 = 0.f, a1 = 0.f, a2 = 0.f, a3 = 0.f;
#pragma unroll
        for (int k = 0; k < CH; ++k) {
            float w = Wup[k * CH + lane];
            a0 = fmaf(nrow[k], w, a0);
            a1 = fmaf(nrow[CH + k], w, a1);
            a2 = fmaf(nrow[2 * CH + k], w, a2);
            a3 = fmaf(nrow[3 * CH + k], w, a3);
        }
        h[(size_t)nb * CH + lane] = a0 * 0.125f;
        h[(size_t)(nb + 1) * CH + lane] = a1 * 0.125f;
        h[(size_t)(nb + 2) * CH + lane] = a2 * 0.125f;
        h[(size_t)(nb + 3) * CH + lane] = a3 * 0.125f;
    } else {
        int e = (bid - PREP_BLKS - H_BLKS) * 256 + t;
        atomicAdd(&counts[recv[e]], 1);
    }
}

// ---------- K_scan: single-block exclusive scan (wave shuffles, 2 barriers) ----
__global__ __launch_bounds__(1024) void k_scan(const int* __restrict__ counts,
                                               int* __restrict__ offsets,
                                               int* __restrict__ cursor) {
    __shared__ int wsum[16];
    int t = threadIdx.x;
    const int CHUNK = 10;  // 1024*10 >= 10000
    int base = t * CHUNK;
    int s = 0;
    for (int i = 0; i < CHUNK; ++i) {
        int idx = base + i;
        if (idx < N_NODES) s += counts[idx];
    }
    int lane = t & 63, wv = t >> 6;
    int x = s;
#pragma unroll
    for (int off = 1; off < 64; off <<= 1) {
        int y = __shfl_up(x, off, 64);
        if (lane >= off) x += y;
    }
    if (lane == 63) wsum[wv] = x;
    __syncthreads();
    if (wv == 0 && lane < 16) {
        int v = wsum[lane];
#pragma unroll
        for (int off = 1; off < 16; off <<= 1) {
            int y = __shfl_up(v, off, 64);
            if (lane >= off) v += y;
        }
        wsum[lane] = v;
    }
    __syncthreads();
    int wbase = (wv == 0) ? 0 : wsum[wv - 1];
    int run = wbase + x - s;
    for (int i = 0; i < CHUNK; ++i) {
        int idx = base + i;
        if (idx < N_NODES) {
            offsets[idx] = run;
            cursor[idx] = run;
            run += counts[idx];
        }
    }
    if (t == 1023) offsets[N_NODES] = wbase + x;
}

// ---------- K_mlp v10: 64 edges/wave (4 A-tiles), pipelined weight loads ----
// 256 thr = 4 waves; 256 edges/block. Each B-fragment feeds 8 independent
// MFMAs per nt (4 tiles x chain-2) -- 2x ILP of v9, half the blocks.
// h-premultiply moved to k_aggdown: k_mlp stores plain w; sender id rides in
// erec's pad word. LDS: act[256][72] bf16 + pos[256] = 37.9 KB (4 blocks/CU).
// NOTE: no min-waves launch bound -- let VGPRs float (forcing it spills).
__global__ __launch_bounds__(256) void k_mlp(const float* __restrict__ ev,
                                             const float* __restrict__ rad,
                                             const unsigned short* __restrict__ wimg,
                                             const int* __restrict__ senders,
                                             const int* __restrict__ recv,
                                             int* __restrict__ cursor,
                                             unsigned short* __restrict__ hw,
                                             float* __restrict__ erec) {
    __shared__ unsigned short act[EPB * ACT_STRIDE];     // 36864 B
    __shared__ int s_pos[EPB];                           // 1024 B

    const int t = threadIdx.x;
    const int e0 = blockIdx.x * EPB;
    const int wv = t >> 6;
    const int lane = t & 63;
    const int lrow = lane & 15;
    const int quad = lane >> 4;
    const int wr0 = wv * 64;                 // this wave's first act row
    int em[4], cr[4];
#pragma unroll
    for (int tt = 0; tt < 4; ++tt) {
        em[tt] = wr0 + tt * 16 + lrow;       // A-tile rows
        cr[tt] = wr0 + tt * 16 + quad * 4;   // C-row bases
    }

    // ---- prefetch: radial frags + W1 (quad 0) + W2 (all lanes) ----
    bf16x8 ar[4];
    bf16x8 bw1[4];
#pragma unroll
    for (int nt = 0; nt < 4; ++nt) {
        ar[nt] = (bf16x8){0, 0, 0, 0, 0, 0, 0, 0};
        bw1[nt] = (bf16x8){0, 0, 0, 0, 0, 0, 0, 0};
    }
    bf16x8 bA[4][2], bB[4][2];
    load_bfrag(bA, wimg + W2_OFF, lrow, quad);           // L2 weights, early
    if (quad == 0) {
#pragma unroll
        for (int tt = 0; tt < 4; ++tt) {
            const float4* rp0 = (const float4*)(rad + (size_t)(e0 + em[tt]) * 8);
            float4 u = rp0[0], v = rp0[1];
            ar[tt][0] = (short)f2bf(u.x); ar[tt][1] = (short)f2bf(u.y);
            ar[tt][2] = (short)f2bf(u.z); ar[tt][3] = (short)f2bf(u.w);
            ar[tt][4] = (short)f2bf(v.x); ar[tt][5] = (short)f2bf(v.y);
            ar[tt][6] = (short)f2bf(v.z); ar[tt][7] = (short)f2bf(v.w);
        }
#pragma unroll
        for (int nt = 0; nt < 4; ++nt)
            bw1[nt] = *(const bf16x8*)(wimg + W1_OFF + (nt * 16 + lrow) * 8);
    }

    // ---- phase 0 (all 64 lanes): CSR position + SH + sender into erec ----
    {
        int e = e0 + wr0 + lane;
        int p = atomicAdd(&cursor[recv[e]], 1);
        s_pos[wr0 + lane] = p;
        int snd = senders[e];
        float vx = ev[(size_t)e * 3 + 0], vy = ev[(size_t)e * 3 + 1], vz = ev[(size_t)e * 3 + 2];
        float inv = rsqrtf(vx * vx + vy * vy + vz * vz);
        float x = vx * inv, y = vy * inv, z = vz * inv;
        const float s3 = 1.7320508075688772f;
        const float s15 = 3.872983346207417f;
        const float s5 = 2.2360679774997896f;
        float4* rp = (float4*)(erec + (size_t)p * EREC);
        rp[0] = make_float4(1.0f, s3 * x, s3 * y, s3 * z);
        rp[1] = make_float4(s15 * x * y, s15 * y * z, 0.5f * s5 * (3.0f * z * z - 1.0f), s15 * x * z);
        rp[2] = make_float4(0.5f * s15 * (x * x - y * y), __int_as_float(snd), 0.f, 0.f);
    }

    // ---- layer 1: [8]->[64] (scale folded into W1), silu ----
#pragma unroll
    for (int nt = 0; nt < 4; ++nt) {
        f32x4 c[4];
#pragma unroll
        for (int tt = 0; tt < 4; ++tt) {
            c[tt] = (f32x4){0.f, 0.f, 0.f, 0.f};
            c[tt] = MFMA16(ar[tt], bw1[nt], c[tt]);
        }
#pragma unroll
        for (int tt = 0; tt < 4; ++tt)
#pragma unroll
            for (int r = 0; r < 4; ++r)
                act[(cr[tt] + r) * ACT_STRIDE + nt * 16 + lrow] = f2bf(silu(c[tt][r]));
    }

    // ---- layer 2 (weights bA); prefetch W3 -> bB first ----
    load_bfrag(bB, wimg + W3_OFF, lrow, quad);
    layer64_t4(act, bA, em, cr, lrow, quad);

    // ---- layer 3 (weights bB); prefetch W4 T=0 -> bA first ----
    load_bfrag(bA, wimg + W4_OFF, lrow, quad);
    layer64_t4(act, bB, em, cr, lrow, quad);

    // ---- layer 4: [64]->[192], 3 thirds, T-pipelined weight loads ----
    {
        bf16x8 a[4][2];
#pragma unroll
        for (int tt = 0; tt < 4; ++tt) {
            a[tt][0] = *(const bf16x8*)(act + em[tt] * ACT_STRIDE + quad * 8);
            a[tt][1] = *(const bf16x8*)(act + em[tt] * ACT_STRIDE + 32 + quad * 8);
        }
        load_bfrag(bB, wimg + W4_OFF + 64 * 72, lrow, quad);       // T=1 weights
        l4_third_t4(act, s_pos, hw, bA, a, cr, 0, wr0, lane, lrow, quad);
        load_bfrag(bA, wimg + W4_OFF + 2 * 64 * 72, lrow, quad);   // T=2 weights
        l4_third_t4(act, s_pos, hw, bB, a, cr, 1, wr0, lane, lrow, quad);
        l4_third_t4(act, s_pos, hw, bA, a, cr, 2, wr0, lane, lrow, quad);
    }
}

// ---------- K_aggdown: streaming CSR aggregation + h apply + linear_down ----
// One wave per node, lane = channel. hw rows coalesced 128B segments; erec
// wave-uniform (scalarized); h row per edge is a coalesced 256B read from
// L2/L3 (h is 2.5 MB). snd rides in erec word 9.
__global__ __launch_bounds__(256, 4) void k_aggdown(const int* __restrict__ offsets,
                                                    const float* __restrict__ erec,
                                                    const unsigned short* __restrict__ hw,
                                                    const float* __restrict__ h,
                                                    const float* __restrict__ Wd,
                                                    float* __restrict__ out) {
    __shared__ float sg[4][576];
    int wv = threadIdx.x >> 6;
    int lane = threadIdx.x & 63;
    int node = __builtin_amdgcn_readfirstlane(blockIdx.x * 4 + wv);
    int s0 = __builtin_amdgcn_readfirstlane(offsets[node]);
    int s1 = __builtin_amdgcn_readfirstlane(offsets[node + 1]);
    float acc[9] = {0.f, 0.f, 0.f, 0.f, 0.f, 0.f, 0.f, 0.f, 0.f};
#pragma unroll 4
    for (int i = s0; i < s1; ++i) {
        const float* rp = erec + (size_t)i * EREC;
        const unsigned short* hrow = hw + (size_t)i * MIXW;
        int snd = __float_as_int(rp[9]);
        float hh = h[(size_t)snd * CH + lane];
        float w0 = bf2f(hrow[lane]) * hh;
        float w1 = bf2f(hrow[64 + lane]) * hh;
        float w2 = bf2f(hrow[128 + lane]) * hh;
        acc[0] += w0 * rp[0];
        acc[1] += w1 * rp[1];
        acc[2] += w1 * rp[2];
        acc[3] += w1 * rp[3];
        acc[4] += w2 * rp[4];
        acc[5] += w2 * rp[5];
        acc[6] += w2 * rp[6];
        acc[7] += w2 * rp[7];
        acc[8] += w2 * rp[8];
    }
    // stash node's agg tile in LDS (per-wave region; in-order DS => no barrier)
    float* arow = sg[wv];
#pragma unroll
    for (int m = 0; m < 9; ++m) arow[lane * 9 + m] = acc[m] * (1.0f / 32.0f);

    // linear_down: lane = output channel d; arow reads broadcast
    float* orow = out + (size_t)node * 576;
    {
        float a = 0.f;
#pragma unroll
        for (int c = 0; c < 64; ++c) a += arow[c * 9] * Wd[c * 64 + lane];
        orow[lane] = a * 0.125f;
    }
    {
        float m3[3] = {0.f, 0.f, 0.f};
#pragma unroll
        for (int c = 0; c < 64; ++c) {
            float w = Wd[(64 + c) * 64 + lane];
#pragma unroll
            for (int mm = 0; mm < 3; ++mm) m3[mm] += arow[c * 9 + 1 + mm] * w;
        }
#pragma unroll
        for (int mm = 0; mm < 3; ++mm) orow[64 + lane * 3 + mm] = m3[mm] * 0.125f;
    }
    {
        float m5[5] = {0.f, 0.f, 0.f, 0.f, 0.f};
#pragma unroll
        for (int c = 0; c < 64; ++c) {
            float w = Wd[(128 + c) * 64 + lane];
#pragma unroll
            for (int mm = 0; mm < 5; ++mm) m5[mm] += arow[c * 9 + 4 + mm] * w;
        }
#pragma unroll
        for (int mm = 0; mm < 5; ++mm) orow[256 + lane * 5 + mm] = m5[mm] * 0.125f;
    }
}

// ---------- launcher ----------
static inline size_t align256(size_t x) { return (x + 255) & ~(size_t)255; }

extern "C" void kernel_launch(void* const* d_in, const int* in_sizes, int n_in,
                              void* d_out, int out_size, void* d_ws, size_t ws_size,
                              hipStream_t stream) {
    const float* edge_vectors = (const float*)d_in[0];
    const float* node_feats   = (const float*)d_in[1];
    const float* radial       = (const float*)d_in[2];
    const int*   senders      = (const int*)d_in[3];
    const int*   receivers    = (const int*)d_in[4];
    const float* W_up         = (const float*)d_in[5];
    const float* W_mlp1       = (const float*)d_in[6];
    const float* W_mlp2       = (const float*)d_in[7];
    const float* W_mlp3       = (const float*)d_in[8];
    const float* W_mlp4       = (const float*)d_in[9];
    const float* W_down       = (const float*)d_in[10];
    float* out = (float*)d_out;

    char* base = (char*)d_ws;
    size_t off = 0;
    float* h = (float*)(base + off);              off = align256(off + (size_t)N_NODES * CH * 4);
    unsigned short* hw = (unsigned short*)(base + off); off = align256(off + (size_t)N_EDGES * MIXW * 2);
    float* erec = (float*)(base + off);           off = align256(off + (size_t)N_EDGES * EREC * 4);
    unsigned short* wimg = (unsigned short*)(base + off); off = align256(off + (size_t)W_TOT * 2);
    int* counts = (int*)(base + off);             off = align256(off + (size_t)N_NODES * 4);
    int* offsets = (int*)(base + off);            off = align256(off + (size_t)(N_NODES + 1) * 4);
    int* cursor = (int*)(base + off);             off = align256(off + (size_t)N_NODES * 4);

    hipMemsetAsync(counts, 0, (size_t)N_NODES * 4, stream);

    k_pre<<<PREP_BLKS + H_BLKS + HIST_BLKS, 256, 0, stream>>>(
        W_mlp1, W_mlp2, W_mlp3, W_mlp4, wimg, node_feats, W_up, h, receivers, counts);
    k_scan<<<1, 1024, 0, stream>>>(counts, offsets, cursor);
    k_mlp<<<N_EDGES / EPB, 256, 0, stream>>>(edge_vectors, radial, wimg, senders,
                                             receivers, cursor, hw, erec);
    k_aggdown<<<N_NODES / 4, 256, 0, stream>>>(offsets, erec, hw, h, W_down, out);
}

// Round 4
// 213.121 us; speedup vs baseline: 1.0288x; 1.0288x over previous
//
#include <hip/hip_runtime.h>
#include <hip/hip_bf16.h>
#include <math.h>

#define N_NODES 10000
#define N_EDGES 320000
#define CH 64
#define MIXW 192    // N_L * CH
#define EREC 16     // floats per edge record: sh[9] + pad -> 64B rows (line-aligned)

// weight-image layout (shorts), stride-72 rows (16B-aligned row starts)
#define W1_OFF 0        // [64][8]
#define W2_OFF 512      // [64][72]
#define W3_OFF 5120     // [64][72]
#define W4_OFF 9728     // [192][72]
#define W_TOT 23552     // shorts
#define ACT_STRIDE 72

#define EPB 256         // edges per k_mlp block (256 thr = 4 waves, 64 edges/wave)

// fused k_pre block ranges
#define PREP_BLKS 92            // 23552/256
#define H_BLKS 625              // 10000 nodes / (4 waves * 4 nodes-per-wave)
#define HIST_BLKS 1250          // 320000/256

typedef __attribute__((ext_vector_type(8))) short bf16x8;
typedef __attribute__((ext_vector_type(4))) float f32x4;
#define MFMA16(a, b, c) __builtin_amdgcn_mfma_f32_16x16x32_bf16(a, b, c, 0, 0, 0)

// ---------- small helpers ----------
__device__ __forceinline__ float bf2f(unsigned short u) {
    union { unsigned int i; float f; } v; v.i = ((unsigned int)u) << 16; return v.f;
}
__device__ __forceinline__ unsigned short f2bf(float f) {
    __hip_bfloat16 b = __float2bfloat16(f);
    return *reinterpret_cast<unsigned short*>(&b);
}
__device__ __forceinline__ float silu(float t) {
    return t * __builtin_amdgcn_rcpf(1.0f + __expf(-t));
}

// load a [64]->[64] layer's B-fragments (8 x b128 from L2-resident wimg)
__device__ __forceinline__ void load_bfrag(bf16x8 (&b)[4][2],
                                           const unsigned short* __restrict__ wbase,
                                           int lrow, int quad) {
#pragma unroll
    for (int nt = 0; nt < 4; ++nt)
#pragma unroll
        for (int kh = 0; kh < 2; ++kh)
            b[nt][kh] = *(const bf16x8*)(wbase + (nt * 16 + lrow) * 72 + kh * 32 + quad * 8);
}

// one in-place [64]->[64] MFMA layer with silu over FOUR 16-edge tiles.
// 8 independent MFMAs per nt -- 2x the ILP of the 2-tile version.
__device__ __forceinline__ void layer64_t4(unsigned short* act, const bf16x8 (&b)[4][2],
                                           const int (&em)[4], const int (&cr)[4],
                                           int lrow, int quad) {
    bf16x8 a[4][2];
#pragma unroll
    for (int t = 0; t < 4; ++t) {
        a[t][0] = *(const bf16x8*)(act + em[t] * ACT_STRIDE + quad * 8);
        a[t][1] = *(const bf16x8*)(act + em[t] * ACT_STRIDE + 32 + quad * 8);
    }
#pragma unroll
    for (int nt = 0; nt < 4; ++nt) {
        f32x4 c[4];
#pragma unroll
        for (int t = 0; t < 4; ++t) {
            c[t] = (f32x4){0.f, 0.f, 0.f, 0.f};
            c[t] = MFMA16(a[t][0], b[nt][0], c[t]);
            c[t] = MFMA16(a[t][1], b[nt][1], c[t]);
        }
#pragma unroll
        for (int t = 0; t < 4; ++t)
#pragma unroll
            for (int r = 0; r < 4; ++r)
                act[(cr[t] + r) * ACT_STRIDE + nt * 16 + lrow] = f2bf(silu(c[t][r]));
    }
}

// one third (64 cols) of layer 4 over 4 tiles: MFMA + h-premult (single
// rounding: f2bf(c*h)) + stage + copyout to hw.
__device__ __forceinline__ void l4_third_t4(unsigned short* act,
                                            const int* s_pos,
                                            unsigned short* __restrict__ hw,
                                            const bf16x8 (&b)[4][2],
                                            const bf16x8 (&a)[4][2],
                                            const float (&hreg)[4][4][4],
                                            const int (&cr)[4],
                                            int T, int wr0, int lane, int lrow, int quad) {
#pragma unroll
    for (int nt = 0; nt < 4; ++nt) {
        f32x4 c[4];
#pragma unroll
        for (int t = 0; t < 4; ++t) {
            c[t] = (f32x4){0.f, 0.f, 0.f, 0.f};
            c[t] = MFMA16(a[t][0], b[nt][0], c[t]);
            c[t] = MFMA16(a[t][1], b[nt][1], c[t]);
        }
#pragma unroll
        for (int t = 0; t < 4; ++t)
#pragma unroll
            for (int r = 0; r < 4; ++r)
                act[(cr[t] + r) * ACT_STRIDE + nt * 16 + lrow] =
                    f2bf(c[t][r] * hreg[t][r][nt]);
    }
    // copy wave's 64 rows x 64 cols -> hw[pos[row]][T*64 .. T*64+64)
#pragma unroll
    for (int j = 0; j < 8; ++j) {
        int idx = lane + 64 * j;          // 0..511
        int row = idx >> 3, c8 = idx & 7;
        int p = s_pos[wr0 + row];
        uint4 v = *(const uint4*)(act + (wr0 + row) * ACT_STRIDE + c8 * 8);
        *(uint4*)(hw + (size_t)p * MIXW + T * 64 + c8 * 8) = v;
    }
}

// ---------- K_pre: fused weight-prep + linear_up + receiver histogram ----------
// Scale folding: W1 *= 1/sqrt(8) (f32, then bf16); W2,W3,W4 *= 1/8 (pow2,
// bit-exact in bf16); h = (nf@Wup)/8 in f32 (linear_up scale).
__global__ __launch_bounds__(256) void k_pre(const float* __restrict__ W1,
                                             const float* __restrict__ W2,
                                             const float* __restrict__ W3,
                                             const float* __restrict__ W4,
                                             unsigned short* __restrict__ wimg,
                                             const float* __restrict__ nf,
                                             const float* __restrict__ Wup,
                                             float* __restrict__ h,
                                             const int* __restrict__ recv,
                                             int* __restrict__ counts) {
    int bid = blockIdx.x;
    int t = threadIdx.x;
    if (bid < PREP_BLKS) {
        int i = bid * 256 + t;
        if (i >= W_TOT) return;
        float v;
        if (i < W2_OFF) {
            int n = i >> 3, k = i & 7;
            v = W1[k * 64 + n] * 0.35355339059327376f;
        } else if (i < W3_OFF) {
            int j = i - W2_OFF; int n = j / 72, k = j % 72;
            v = (k < 64) ? W2[k * 64 + n] * 0.125f : 0.f;
        } else if (i < W4_OFF) {
            int j = i - W3_OFF; int n = j / 72, k = j % 72;
            v = (k < 64) ? W3[k * 64 + n] * 0.125f : 0.f;
        } else {
            int j = i - W4_OFF; int n = j / 72, k = j % 72;
            v = (k < 64) ? W4[k * MIXW + n] * 0.125f : 0.f;
        }
        wimg[i] = f2bf(v);
    } else if (bid < PREP_BLKS + H_BLKS) {
        // linear_up: 4 nodes per wave -- Wup column loaded once, 4 indep chains
        int nb = __builtin_amdgcn_readfirstlane(
            (bid - PREP_BLKS) * 16 + (t >> 6) * 4);
        int lane = t & 63;
        const float* nrow = nf + (size_t)nb * CH;
        float a0 = 0.f, a1 = 0.f, a2 = 0.f, a3 = 0.f;
#pragma unroll
        for (int k = 0; k < CH; ++k) {
            float w = Wup[k * CH + lane];
            a0 = fmaf(nrow[k], w, a0);
            a1 = fmaf(nrow[CH + k], w, a1);
            a2 = fmaf(nrow[2 * CH + k], w, a2);
            a3 = fmaf(nrow[3 * CH + k], w, a3);
        }
        h[(size_t)nb * CH + lane] = a0 * 0.125f;
        h[(size_t)(nb + 1) * CH + lane] = a1 * 0.125f;
        h[(size_t)(nb + 2) * CH + lane] = a2 * 0.125f;
        h[(size_t)(nb + 3) * CH + lane] = a3 * 0.125f;
    } else {
        int e = (bid - PREP_BLKS - H_BLKS) * 256 + t;
        atomicAdd(&counts[recv[e]], 1);
    }
}

// ---------- K_scan: single-block exclusive scan (wave shuffles, 2 barriers) ----
__global__ __launch_bounds__(1024) void k_scan(const int* __restrict__ counts,
                                               int* __restrict__ offsets,
                                               int* __restrict__ cursor) {
    __shared__ int wsum[16];
    int t = threadIdx.x;
    const int CHUNK = 10;  // 1024*10 >= 10000
    int base = t * CHUNK;
    int s = 0;
    for (int i = 0; i < CHUNK; ++i) {
        int idx = base + i;
        if (idx < N_NODES) s += counts[idx];
    }
    int lane = t & 63, wv = t >> 6;
    int x = s;
#pragma unroll
    for (int off = 1; off < 64; off <<= 1) {
        int y = __shfl_up(x, off, 64);
        if (lane >= off) x += y;
    }
    if (lane == 63) wsum[wv] = x;
    __syncthreads();
    if (wv == 0 && lane < 16) {
        int v = wsum[lane];
#pragma unroll
        for (int off = 1; off < 16; off <<= 1) {
            int y = __shfl_up(v, off, 64);
            if (lane >= off) v += y;
        }
        wsum[lane] = v;
    }
    __syncthreads();
    int wbase = (wv == 0) ? 0 : wsum[wv - 1];
    int run = wbase + x - s;
    for (int i = 0; i < CHUNK; ++i) {
        int idx = base + i;
        if (idx < N_NODES) {
            offsets[idx] = run;
            cursor[idx] = run;
            run += counts[idx];
        }
    }
    if (t == 1023) offsets[N_NODES] = wbase + x;
}

// ---------- K_mlp v11: 64 edges/wave (4 A-tiles) + in-kernel h-premult ----
// 256 thr = 4 waves; 256 edges/block. h gather (64 dwords/lane, L2-resident,
// coalesced 64B per quad-group) issued after layer 3, consumed at L4 C-store
// (single-rounding f2bf(c*h)). LDS: act[256][72] + pos[256] + snd[256] = 38.9 KB.
// NOTE: no min-waves launch bound -- let VGPRs float (forcing it spills).
__global__ __launch_bounds__(256) void k_mlp(const float* __restrict__ ev,
                                             const float* __restrict__ rad,
                                             const unsigned short* __restrict__ wimg,
                                             const int* __restrict__ senders,
                                             const int* __restrict__ recv,
                                             int* __restrict__ cursor,
                                             const float* __restrict__ h,
                                             unsigned short* __restrict__ hw,
                                             float* __restrict__ erec) {
    __shared__ unsigned short act[EPB * ACT_STRIDE];     // 36864 B
    __shared__ int s_pos[EPB];                           // 1024 B
    __shared__ int s_snd[EPB];                           // 1024 B

    const int t = threadIdx.x;
    const int e0 = blockIdx.x * EPB;
    const int wv = t >> 6;
    const int lane = t & 63;
    const int lrow = lane & 15;
    const int quad = lane >> 4;
    const int wr0 = wv * 64;                 // this wave's first act row
    int em[4], cr[4];
#pragma unroll
    for (int tt = 0; tt < 4; ++tt) {
        em[tt] = wr0 + tt * 16 + lrow;       // A-tile rows
        cr[tt] = wr0 + tt * 16 + quad * 4;   // C-row bases
    }

    // ---- prefetch: radial frags + W1 (quad 0) + W2 (all lanes) ----
    bf16x8 ar[4];
    bf16x8 bw1[4];
#pragma unroll
    for (int nt = 0; nt < 4; ++nt) {
        ar[nt] = (bf16x8){0, 0, 0, 0, 0, 0, 0, 0};
        bw1[nt] = (bf16x8){0, 0, 0, 0, 0, 0, 0, 0};
    }
    bf16x8 bA[4][2], bB[4][2];
    load_bfrag(bA, wimg + W2_OFF, lrow, quad);           // L2 weights, early
    if (quad == 0) {
#pragma unroll
        for (int tt = 0; tt < 4; ++tt) {
            const float4* rp0 = (const float4*)(rad + (size_t)(e0 + em[tt]) * 8);
            float4 u = rp0[0], v = rp0[1];
            ar[tt][0] = (short)f2bf(u.x); ar[tt][1] = (short)f2bf(u.y);
            ar[tt][2] = (short)f2bf(u.z); ar[tt][3] = (short)f2bf(u.w);
            ar[tt][4] = (short)f2bf(v.x); ar[tt][5] = (short)f2bf(v.y);
            ar[tt][6] = (short)f2bf(v.z); ar[tt][7] = (short)f2bf(v.w);
        }
#pragma unroll
        for (int nt = 0; nt < 4; ++nt)
            bw1[nt] = *(const bf16x8*)(wimg + W1_OFF + (nt * 16 + lrow) * 8);
    }

    // ---- phase 0 (all 64 lanes): CSR position + sender + SH (64B rows) ----
    {
        int e = e0 + wr0 + lane;
        int p = atomicAdd(&cursor[recv[e]], 1);
        s_pos[wr0 + lane] = p;
        s_snd[wr0 + lane] = senders[e];
        float vx = ev[(size_t)e * 3 + 0], vy = ev[(size_t)e * 3 + 1], vz = ev[(size_t)e * 3 + 2];
        float inv = rsqrtf(vx * vx + vy * vy + vz * vz);
        float x = vx * inv, y = vy * inv, z = vz * inv;
        const float s3 = 1.7320508075688772f;
        const float s15 = 3.872983346207417f;
        const float s5 = 2.2360679774997896f;
        float4* rp = (float4*)(erec + (size_t)p * EREC);
        rp[0] = make_float4(1.0f, s3 * x, s3 * y, s3 * z);
        rp[1] = make_float4(s15 * x * y, s15 * y * z, 0.5f * s5 * (3.0f * z * z - 1.0f), s15 * x * z);
        rp[2] = make_float4(0.5f * s15 * (x * x - y * y), 0.f, 0.f, 0.f);
        rp[3] = make_float4(0.f, 0.f, 0.f, 0.f);   // full 64B line written: no RMW
    }

    // ---- layer 1: [8]->[64] (scale folded into W1), silu ----
#pragma unroll
    for (int nt = 0; nt < 4; ++nt) {
        f32x4 c[4];
#pragma unroll
        for (int tt = 0; tt < 4; ++tt) {
            c[tt] = (f32x4){0.f, 0.f, 0.f, 0.f};
            c[tt] = MFMA16(ar[tt], bw1[nt], c[tt]);
        }
#pragma unroll
        for (int tt = 0; tt < 4; ++tt)
#pragma unroll
            for (int r = 0; r < 4; ++r)
                act[(cr[tt] + r) * ACT_STRIDE + nt * 16 + lrow] = f2bf(silu(c[tt][r]));
    }

    // ---- layer 2 (weights bA); prefetch W3 -> bB first ----
    load_bfrag(bB, wimg + W3_OFF, lrow, quad);
    layer64_t4(act, bA, em, cr, lrow, quad);

    // ---- layer 3 (weights bB); prefetch W4 T=0 -> bA + sender ids first ----
    load_bfrag(bA, wimg + W4_OFF, lrow, quad);
    int sn[4][4];
#pragma unroll
    for (int tt = 0; tt < 4; ++tt)
#pragma unroll
        for (int r = 0; r < 4; ++r)
            sn[tt][r] = s_snd[cr[tt] + r];
    layer64_t4(act, bB, em, cr, lrow, quad);

    // ---- h gather: 64 dwords/lane; each (row,nt) 16-lane group reads a
    //      contiguous 64B segment from L2-resident h. Consumed at L4 C-store.
    float hreg[4][4][4];
#pragma unroll
    for (int tt = 0; tt < 4; ++tt)
#pragma unroll
        for (int r = 0; r < 4; ++r) {
            const float* hb = h + (size_t)sn[tt][r] * CH + lrow;
#pragma unroll
            for (int nt = 0; nt < 4; ++nt)
                hreg[tt][r][nt] = hb[nt * 16];
        }

    // ---- layer 4: [64]->[192], 3 thirds, T-pipelined weight loads ----
    {
        bf16x8 a[4][2];
#pragma unroll
        for (int tt = 0; tt < 4; ++tt) {
            a[tt][0] = *(const bf16x8*)(act + em[tt] * ACT_STRIDE + quad * 8);
            a[tt][1] = *(const bf16x8*)(act + em[tt] * ACT_STRIDE + 32 + quad * 8);
        }
        load_bfrag(bB, wimg + W4_OFF + 64 * 72, lrow, quad);       // T=1 weights
        l4_third_t4(act, s_pos, hw, bA, a, hreg, cr, 0, wr0, lane, lrow, quad);
        load_bfrag(bA, wimg + W4_OFF + 2 * 64 * 72, lrow, quad);   // T=2 weights
        l4_third_t4(act, s_pos, hw, bB, a, hreg, cr, 1, wr0, lane, lrow, quad);
        l4_third_t4(act, s_pos, hw, bA, a, hreg, cr, 2, wr0, lane, lrow, quad);
    }
}

// ---------- K_aggdown: pure-streaming CSR aggregation + fused linear_down ----
// One wave per node, lane = channel. hw rows coalesced 128B segments; erec
// rows 64B line-aligned, wave-uniform (scalarized). No gathers, no chains.
__global__ __launch_bounds__(256, 4) void k_aggdown(const int* __restrict__ offsets,
                                                    const float* __restrict__ erec,
                                                    const unsigned short* __restrict__ hw,
                                                    const float* __restrict__ Wd,
                                                    float* __restrict__ out) {
    __shared__ float sg[4][576];
    int wv = threadIdx.x >> 6;
    int lane = threadIdx.x & 63;
    int node = __builtin_amdgcn_readfirstlane(blockIdx.x * 4 + wv);
    int s0 = __builtin_amdgcn_readfirstlane(offsets[node]);
    int s1 = __builtin_amdgcn_readfirstlane(offsets[node + 1]);
    float acc[9] = {0.f, 0.f, 0.f, 0.f, 0.f, 0.f, 0.f, 0.f, 0.f};
#pragma unroll 8
    for (int i = s0; i < s1; ++i) {
        const float* rp = erec + (size_t)i * EREC;
        const unsigned short* hrow = hw + (size_t)i * MIXW;
        float w0 = bf2f(hrow[lane]);
        float w1 = bf2f(hrow[64 + lane]);
        float w2 = bf2f(hrow[128 + lane]);
        acc[0] += w0 * rp[0];
        acc[1] += w1 * rp[1];
        acc[2] += w1 * rp[2];
        acc[3] += w1 * rp[3];
        acc[4] += w2 * rp[4];
        acc[5] += w2 * rp[5];
        acc[6] += w2 * rp[6];
        acc[7] += w2 * rp[7];
        acc[8] += w2 * rp[8];
    }
    // stash node's agg tile in LDS (per-wave region; in-order DS => no barrier)
    float* arow = sg[wv];
#pragma unroll
    for (int m = 0; m < 9; ++m) arow[lane * 9 + m] = acc[m] * (1.0f / 32.0f);

    // linear_down: lane = output channel d; arow reads broadcast
    float* orow = out + (size_t)node * 576;
    {
        float a = 0.f;
#pragma unroll
        for (int c = 0; c < 64; ++c) a += arow[c * 9] * Wd[c * 64 + lane];
        orow[lane] = a * 0.125f;
    }
    {
        float m3[3] = {0.f, 0.f, 0.f};
#pragma unroll
        for (int c = 0; c < 64; ++c) {
            float w = Wd[(64 + c) * 64 + lane];
#pragma unroll
            for (int mm = 0; mm < 3; ++mm) m3[mm] += arow[c * 9 + 1 + mm] * w;
        }
#pragma unroll
        for (int mm = 0; mm < 3; ++mm) orow[64 + lane * 3 + mm] = m3[mm] * 0.125f;
    }
    {
        float m5[5] = {0.f, 0.f, 0.f, 0.f, 0.f};
#pragma unroll
        for (int c = 0; c < 64; ++c) {
            float w = Wd[(128 + c) * 64 + lane];
#pragma unroll
            for (int mm = 0; mm < 5; ++mm) m5[mm] += arow[c * 9 + 4 + mm] * w;
        }
#pragma unroll
        for (int mm = 0; mm < 5; ++mm) orow[256 + lane * 5 + mm] = m5[mm] * 0.125f;
    }
}

// ---------- launcher ----------
static inline size_t align256(size_t x) { return (x + 255) & ~(size_t)255; }

extern "C" void kernel_launch(void* const* d_in, const int* in_sizes, int n_in,
                              void* d_out, int out_size, void* d_ws, size_t ws_size,
                              hipStream_t stream) {
    const float* edge_vectors = (const float*)d_in[0];
    const float* node_feats   = (const float*)d_in[1];
    const float* radial       = (const float*)d_in[2];
    const int*   senders      = (const int*)d_in[3];
    const int*   receivers    = (const int*)d_in[4];
    const float* W_up         = (const float*)d_in[5];
    const float* W_mlp1       = (const float*)d_in[6];
    const float* W_mlp2       = (const float*)d_in[7];
    const float* W_mlp3       = (const float*)d_in[8];
    const float* W_mlp4       = (const float*)d_in[9];
    const float* W_down       = (const float*)d_in[10];
    float* out = (float*)d_out;

    char* base = (char*)d_ws;
    size_t off = 0;
    float* h = (float*)(base + off);              off = align256(off + (size_t)N_NODES * CH * 4);
    unsigned short* hw = (unsigned short*)(base + off); off = align256(off + (size_t)N_EDGES * MIXW * 2);
    float* erec = (float*)(base + off);           off = align256(off + (size_t)N_EDGES * EREC * 4);
    unsigned short* wimg = (unsigned short*)(base + off); off = align256(off + (size_t)W_TOT * 2);
    int* counts = (int*)(base + off);             off = align256(off + (size_t)N_NODES * 4);
    int* offsets = (int*)(base + off);            off = align256(off + (size_t)(N_NODES + 1) * 4);
    int* cursor = (int*)(base + off);             off = align256(off + (size_t)N_NODES * 4);

    hipMemsetAsync(counts, 0, (size_t)N_NODES * 4, stream);

    k_pre<<<PREP_BLKS + H_BLKS + HIST_BLKS, 256, 0, stream>>>(
        W_mlp1, W_mlp2, W_mlp3, W_mlp4, wimg, node_feats, W_up, h, receivers, counts);
    k_scan<<<1, 1024, 0, stream>>>(counts, offsets, cursor);
    k_mlp<<<N_EDGES / EPB, 256, 0, stream>>>(edge_vectors, radial, wimg, senders,
                                             receivers, cursor, h, hw, erec);
    k_aggdown<<<N_NODES / 4, 256, 0, stream>>>(offsets, erec, hw, W_down, out);
}